// Round 2
// baseline (1123.285 us; speedup 1.0000x reference)
//
#include <hip/hip_runtime.h>

// TransformerLayer_Combined: S=1024, B=4, H=1024, NH=16, HPH=64, NF=4, DIN=256,
// DHID=2048, DH2=1024. Inputs fp32, outputs fp32 (out0 [S,B,H], out1 [64,S,S]).

// ---------------- LayerNorm over H=1024 (one block per row) ----------------
__global__ __launch_bounds__(256) void ln1_kernel(
    const float* __restrict__ x, const float* __restrict__ g,
    const float* __restrict__ b, float* __restrict__ y)
{
  const long base = (long)blockIdx.x * 1024;
  const int c = threadIdx.x * 4;
  float4 v = *(const float4*)(x + base + c);
  float s = v.x + v.y + v.z + v.w;
  float ss = v.x*v.x + v.y*v.y + v.z*v.z + v.w*v.w;
  #pragma unroll
  for (int off = 32; off > 0; off >>= 1) {
    s  += __shfl_xor(s, off);
    ss += __shfl_xor(ss, off);
  }
  __shared__ float sw[4], ssw[4];
  const int wave = threadIdx.x >> 6;
  if ((threadIdx.x & 63) == 0) { sw[wave] = s; ssw[wave] = ss; }
  __syncthreads();
  s  = sw[0] + sw[1] + sw[2] + sw[3];
  ss = ssw[0] + ssw[1] + ssw[2] + ssw[3];
  const float mean = s * (1.0f/1024.0f);
  const float var  = ss * (1.0f/1024.0f) - mean*mean;
  const float rs   = rsqrtf(var + 1e-6f);
  const float4 gv = *(const float4*)(g + c);
  const float4 bv = *(const float4*)(b + c);
  float4 o;
  o.x = (v.x - mean) * rs * gv.x + bv.x;
  o.y = (v.y - mean) * rs * gv.y + bv.y;
  o.z = (v.z - mean) * rs * gv.z + bv.z;
  o.w = (v.w - mean) * rs * gv.w + bv.w;
  *(float4*)(y + base + c) = o;
}

// ------------- generic fp32 GEMM: C = A@B + bias, 64x64 tile --------------
// grid (N/64, M/64, groups).
__global__ __launch_bounds__(256) void gemm_bias_kernel(
    const float* __restrict__ A, int lda, int ags,
    const float* __restrict__ B, int ldb, int bgs,
    const float* __restrict__ bias, int biasgs,
    float* __restrict__ C, int ldc, int cgs, int K)
{
  const int g = blockIdx.z;
  const float* Ag = A + (long)g * ags;
  const float* Bg = B + (long)g * bgs;
  const float* biasg = bias + (long)g * biasgs;
  const int row0 = blockIdx.y * 64, col0 = blockIdx.x * 64;
  __shared__ float As[16][68];   // As[k][m]
  __shared__ float Bs[16][68];   // Bs[k][n]
  const int tid = threadIdx.x;
  const int tx = tid & 15, ty = tid >> 4;
  const int lr = tid >> 2, lk = (tid & 3) << 2;
  const int bk = tid >> 4, bc = (tid & 15) << 2;
  float acc[4][4] = {};
  for (int k0 = 0; k0 < K; k0 += 16) {
    float4 a4 = *(const float4*)(Ag + (long)(row0 + lr) * lda + k0 + lk);
    As[lk+0][lr] = a4.x; As[lk+1][lr] = a4.y; As[lk+2][lr] = a4.z; As[lk+3][lr] = a4.w;
    float4 b4 = *(const float4*)(Bg + (long)(k0 + bk) * ldb + col0 + bc);
    *(float4*)&Bs[bk][bc] = b4;
    __syncthreads();
    #pragma unroll
    for (int kk = 0; kk < 16; ++kk) {
      const float4 ar = *(const float4*)&As[kk][ty << 2];
      const float4 br = *(const float4*)&Bs[kk][tx << 2];
      const float a0[4] = {ar.x, ar.y, ar.z, ar.w};
      const float b0[4] = {br.x, br.y, br.z, br.w};
      #pragma unroll
      for (int i = 0; i < 4; ++i)
        #pragma unroll
        for (int j = 0; j < 4; ++j)
          acc[i][j] = fmaf(a0[i], b0[j], acc[i][j]);
    }
    __syncthreads();
  }
  const float4 biv = *(const float4*)(biasg + col0 + (tx << 2));
  const float bb[4] = {biv.x, biv.y, biv.z, biv.w};
  #pragma unroll
  for (int i = 0; i < 4; ++i) {
    const long rr = row0 + (ty << 2) + i;
    const long ob = (long)g * cgs + rr * ldc + col0 + (tx << 2);
    float4 o = make_float4(acc[i][0]+bb[0], acc[i][1]+bb[1],
                           acc[i][2]+bb[2], acc[i][3]+bb[3]);
    *(float4*)(C + ob) = o;
  }
}

// ------------- attention: gaussian-kernel scores + exp + PV ---------------
// grid (S/64, B*NH). q,k,v are [S*B][H] flats; scores is out1 [64][1024][1024] f32.
__global__ __launch_bounds__(256) void attn_kernel(
    const float* __restrict__ qf, const float* __restrict__ kf,
    const float* __restrict__ vf, float* __restrict__ ctx,
    float* __restrict__ scores)
{
  const int n = blockIdx.y;          // head index b*16+h
  const int s0 = blockIdx.x * 64;
  const int b = n >> 4, h = n & 15;
  const int hoff = h * 64;
  __shared__ float QsT[64][68];      // QsT[d][r]
  __shared__ float KsT[64][68];      // KsT[d][t]
  __shared__ float Vs[64][68];       // Vs[t][d]
  __shared__ float PsT[64][68];      // PsT[t][r]
  __shared__ float q2s[64], k2s[64];
  const int tid = threadIdx.x;
  const int tx = tid & 15, ty = tid >> 4;

  #pragma unroll
  for (int p = 0; p < 4; ++p) {
    const int r = (tid >> 4) + p * 16;
    const int d4 = (tid & 15) * 4;
    const float4 t4 = *(const float4*)(qf + ((long)((s0 + r) * 4 + b)) * 1024 + hoff + d4);
    QsT[d4+0][r] = t4.x; QsT[d4+1][r] = t4.y; QsT[d4+2][r] = t4.z; QsT[d4+3][r] = t4.w;
  }
  __syncthreads();
  if (tid < 64) {
    float s = 0.f;
    #pragma unroll
    for (int d = 0; d < 64; ++d) { const float v = QsT[d][tid]; s = fmaf(v, v, s); }
    q2s[tid] = s;
  }

  float acc[4][4] = {};

  for (int t0 = 0; t0 < 1024; t0 += 64) {
    #pragma unroll
    for (int p = 0; p < 4; ++p) {
      const int t = (tid >> 4) + p * 16;
      const int d4 = (tid & 15) * 4;
      const long base = ((long)((t0 + t) * 4 + b)) * 1024 + hoff + d4;
      const float4 k4 = *(const float4*)(kf + base);
      KsT[d4+0][t] = k4.x; KsT[d4+1][t] = k4.y; KsT[d4+2][t] = k4.z; KsT[d4+3][t] = k4.w;
      const float4 v4 = *(const float4*)(vf + base);
      *(float4*)&Vs[t][d4] = v4;
    }
    __syncthreads();
    if (tid < 64) {
      float s = 0.f;
      #pragma unroll
      for (int d = 0; d < 64; ++d) { const float v = KsT[d][tid]; s = fmaf(v, v, s); }
      k2s[tid] = s;
    }
    __syncthreads();

    float qk[4][4] = {};
    #pragma unroll 8
    for (int d = 0; d < 64; ++d) {
      const float4 qr = *(const float4*)&QsT[d][ty << 2];
      const float4 kr = *(const float4*)&KsT[d][tx << 2];
      const float q0[4] = {qr.x, qr.y, qr.z, qr.w};
      const float k0[4] = {kr.x, kr.y, kr.z, kr.w};
      #pragma unroll
      for (int i = 0; i < 4; ++i)
        #pragma unroll
        for (int j = 0; j < 4; ++j)
          qk[i][j] = fmaf(q0[i], k0[j], qk[i][j]);
    }
    const float k2r[4] = {k2s[(tx<<2)+0], k2s[(tx<<2)+1], k2s[(tx<<2)+2], k2s[(tx<<2)+3]};
    #pragma unroll
    for (int i = 0; i < 4; ++i) {
      const int row = (ty << 2) + i;
      const float q2v = q2s[row];
      float4 mk;
      float* mp = &mk.x;
      #pragma unroll
      for (int j = 0; j < 4; ++j) {
        const float m = (2.0f * qk[i][j] - q2v - k2r[j]) * 0.0625f;
        mp[j] = m;
        PsT[(tx << 2) + j][row] = __expf(m);
      }
      *(float4*)(scores + (long)n * 1048576 + (long)(s0 + row) * 1024 + t0 + (tx << 2)) = mk;
    }
    __syncthreads();

    #pragma unroll 8
    for (int t = 0; t < 64; ++t) {
      const float4 pr = *(const float4*)&PsT[t][ty << 2];
      const float4 vr = *(const float4*)&Vs[t][tx << 2];
      const float p0[4] = {pr.x, pr.y, pr.z, pr.w};
      const float v0[4] = {vr.x, vr.y, vr.z, vr.w};
      #pragma unroll
      for (int i = 0; i < 4; ++i)
        #pragma unroll
        for (int j = 0; j < 4; ++j)
          acc[i][j] = fmaf(p0[i], v0[j], acc[i][j]);
    }
    __syncthreads();
  }

  #pragma unroll
  for (int i = 0; i < 4; ++i) {
    const int row = s0 + (ty << 2) + i;
    *(float4*)(ctx + ((long)(row * 4 + b)) * 1024 + hoff + (tx << 2)) =
        make_float4(acc[i][0], acc[i][1], acc[i][2], acc[i][3]);
  }
}

// -------- residual (with LN1 output) + per-head (64-wide) LayerNorm --------
__global__ __launch_bounds__(256) void ln2res_kernel(
    const float* __restrict__ xln, float* __restrict__ ctx,
    const float* __restrict__ g2, const float* __restrict__ b2)
{
  const int lane = threadIdx.x & 63;
  const long row = (long)blockIdx.x * 4 + (threadIdx.x >> 6);
  const long idx = row * 64 + lane;
  const float v = xln[idx] + ctx[idx];
  float s = v, ss = v * v;
  #pragma unroll
  for (int off = 32; off > 0; off >>= 1) {
    s  += __shfl_xor(s, off);
    ss += __shfl_xor(ss, off);
  }
  const float mean = s * (1.0f/64.0f);
  const float var  = ss * (1.0f/64.0f) - mean*mean;
  const float rs   = rsqrtf(var + 1e-6f);
  ctx[idx] = (v - mean) * rs * g2[lane] + b2[lane];
}

// -------- grouped FFN dense_in fused with GLU: h2 = xh * relu(yh) ---------
// grid (1024/64, 4096/64, 4)
__global__ __launch_bounds__(256) void gemm_glu_kernel(
    const float* __restrict__ A,   // ctx2 [4096][1024], group col offset g*256
    const float* __restrict__ W,   // W_in [4][256][2048]
    const float* __restrict__ bin, // [4][2048]
    float* __restrict__ H2)        // [4096][4096] = [row][g*1024+o]
{
  const int g = blockIdx.z;
  const float* Ag = A + g * 256;
  const float* Wg = W + (long)g * 256 * 2048;
  const float* bg = bin + g * 2048;
  const int row0 = blockIdx.y * 64, col0 = blockIdx.x * 64;
  __shared__ float As[16][68], Bx[16][68], By[16][68];
  const int tid = threadIdx.x, tx = tid & 15, ty = tid >> 4;
  const int lr = tid >> 2, lk = (tid & 3) << 2;
  const int bk = tid >> 4, bc = (tid & 15) << 2;
  float ax[4][4] = {}, ay[4][4] = {};
  for (int k0 = 0; k0 < 256; k0 += 16) {
    float4 a4 = *(const float4*)(Ag + (long)(row0 + lr) * 1024 + k0 + lk);
    As[lk+0][lr]=a4.x; As[lk+1][lr]=a4.y; As[lk+2][lr]=a4.z; As[lk+3][lr]=a4.w;
    float4 x4 = *(const float4*)(Wg + (long)(k0 + bk) * 2048 + col0 + bc);
    *(float4*)&Bx[bk][bc] = x4;
    float4 y4 = *(const float4*)(Wg + (long)(k0 + bk) * 2048 + 1024 + col0 + bc);
    *(float4*)&By[bk][bc] = y4;
    __syncthreads();
    #pragma unroll
    for (int kk = 0; kk < 16; ++kk) {
      const float4 ar = *(const float4*)&As[kk][ty << 2];
      const float4 xr = *(const float4*)&Bx[kk][tx << 2];
      const float4 yr = *(const float4*)&By[kk][tx << 2];
      const float a0[4] = {ar.x, ar.y, ar.z, ar.w};
      const float x0[4] = {xr.x, xr.y, xr.z, xr.w};
      const float y0[4] = {yr.x, yr.y, yr.z, yr.w};
      #pragma unroll
      for (int i = 0; i < 4; ++i)
        #pragma unroll
        for (int j = 0; j < 4; ++j) {
          ax[i][j] = fmaf(a0[i], x0[j], ax[i][j]);
          ay[i][j] = fmaf(a0[i], y0[j], ay[i][j]);
        }
    }
    __syncthreads();
  }
  const float4 bxv = *(const float4*)(bg + col0 + (tx << 2));
  const float4 byv = *(const float4*)(bg + 1024 + col0 + (tx << 2));
  const float bx0[4] = {bxv.x, bxv.y, bxv.z, bxv.w};
  const float by0[4] = {byv.x, byv.y, byv.z, byv.w};
  #pragma unroll
  for (int i = 0; i < 4; ++i) {
    const long rr = row0 + (ty << 2) + i;
    float4 o;
    float* op = &o.x;
    #pragma unroll
    for (int j = 0; j < 4; ++j) {
      const float xh = ax[i][j] + bx0[j];
      const float yh = ay[i][j] + by0[j];
      op[j] = xh * fmaxf(yh, 0.0f);
    }
    *(float4*)(H2 + rr * 4096 + g * 1024 + col0 + (tx << 2)) = o;
  }
}

extern "C" void kernel_launch(void* const* d_in, const int* in_sizes, int n_in,
                              void* d_out, int out_size, void* d_ws, size_t ws_size,
                              hipStream_t stream) {
  const float* hs   = (const float*)d_in[0];
  const float* g1   = (const float*)d_in[1];
  const float* b1   = (const float*)d_in[2];
  const float* g2   = (const float*)d_in[3];
  const float* b2   = (const float*)d_in[4];
  const float* Wq   = (const float*)d_in[5];
  const float* bq   = (const float*)d_in[6];
  const float* Wk   = (const float*)d_in[7];
  const float* bk   = (const float*)d_in[8];
  const float* Wv   = (const float*)d_in[9];
  const float* bv   = (const float*)d_in[10];
  const float* Win  = (const float*)d_in[11];
  const float* bin  = (const float*)d_in[12];
  const float* Wout = (const float*)d_in[13];
  const float* bout = (const float*)d_in[14];
  const float* Wd   = (const float*)d_in[15];
  const float* bd   = (const float*)d_in[16];

  // workspace layout (fp32), total 25,165,824 floats = ~100.7 MB.
  // h2 overlays xln/qf/kf/vf (all dead by the time gemm_glu runs).
  float* xln = (float*)d_ws;            // [4096][1024]
  float* qf  = xln + 4194304;           // [4096][1024]
  float* kf  = qf  + 4194304;
  float* vf  = kf  + 4194304;
  float* h2  = (float*)d_ws;            // [4096][4096], reuses [0, 16.78M floats)
  float* ctx = (float*)d_ws + 16777216; // [4096][1024]; ctx2 in place
  float* og  = ctx + 4194304;           // [4096][1024]

  float* out0 = (float*)d_out;          // [S,B,H] f32
  float* out1 = out0 + 4194304;         // [64,1024,1024] f32

  ln1_kernel<<<4096, 256, 0, stream>>>(hs, g1, b1, xln);

  dim3 gq(16, 64, 1);
  gemm_bias_kernel<<<gq, 256, 0, stream>>>(xln, 1024, 0, Wq, 1024, 0, bq, 0,
                                           qf, 1024, 0, 1024);
  gemm_bias_kernel<<<gq, 256, 0, stream>>>(xln, 1024, 0, Wk, 1024, 0, bk, 0,
                                           kf, 1024, 0, 1024);
  gemm_bias_kernel<<<gq, 256, 0, stream>>>(xln, 1024, 0, Wv, 1024, 0, bv, 0,
                                           vf, 1024, 0, 1024);

  attn_kernel<<<dim3(16, 64), 256, 0, stream>>>(qf, kf, vf, ctx, out1);

  ln2res_kernel<<<16384, 256, 0, stream>>>(xln, ctx, g2, b2);

  gemm_glu_kernel<<<dim3(16, 64, 4), 256, 0, stream>>>(ctx, Win, bin, h2);

  gemm_bias_kernel<<<dim3(4, 64, 4), 256, 0, stream>>>(
      h2, 4096, 1024, Wout, 256, 1024 * 256, bout, 256,
      og, 1024, 256, 1024);

  gemm_bias_kernel<<<gq, 256, 0, stream>>>(og, 1024, 0, Wd, 1024, 0, bd, 0,
                                           out0, 1024, 0, 1024);
}

// Round 5
// 280.789 us; speedup vs baseline: 4.0005x; 4.0005x over previous
//
#include <hip/hip_runtime.h>

// TransformerLayer_Combined on gfx950 — bf16 MFMA pipeline.
// S=1024,B=4,H=1024,NH=16,HPH=64,NF=4,DIN=256,DHID=2048. Outputs fp32.

typedef __attribute__((ext_vector_type(8))) short short8;
typedef __attribute__((ext_vector_type(4))) float f32x4;

__device__ __forceinline__ unsigned short f2bf(float f) {
  union { float f; unsigned u; } x; x.f = f;
  unsigned r = x.u + 0x7FFFu + ((x.u >> 16) & 1u);
  return (unsigned short)(r >> 16);
}
__device__ __forceinline__ float bf2f(unsigned short u) {
  union { float f; unsigned u; } x; x.u = ((unsigned)u) << 16;
  return x.f;
}

// ---------------- LN1 over H=1024: writes fp32 (residual) + bf16 (GEMM A) ----
__global__ __launch_bounds__(256) void ln1_kernel(
    const float* __restrict__ x, const float* __restrict__ g,
    const float* __restrict__ b, float* __restrict__ y,
    unsigned short* __restrict__ ybf)
{
  const long base = (long)blockIdx.x * 1024;
  const int c = threadIdx.x * 4;
  float4 v = *(const float4*)(x + base + c);
  float s = v.x + v.y + v.z + v.w;
  float ss = v.x*v.x + v.y*v.y + v.z*v.z + v.w*v.w;
  #pragma unroll
  for (int off = 32; off > 0; off >>= 1) {
    s  += __shfl_xor(s, off);
    ss += __shfl_xor(ss, off);
  }
  __shared__ float sw[4], ssw[4];
  const int wave = threadIdx.x >> 6;
  if ((threadIdx.x & 63) == 0) { sw[wave] = s; ssw[wave] = ss; }
  __syncthreads();
  s  = sw[0] + sw[1] + sw[2] + sw[3];
  ss = ssw[0] + ssw[1] + ssw[2] + ssw[3];
  const float mean = s * (1.0f/1024.0f);
  const float var  = ss * (1.0f/1024.0f) - mean*mean;
  const float rs   = rsqrtf(var + 1e-6f);
  const float4 gv = *(const float4*)(g + c);
  const float4 bv = *(const float4*)(b + c);
  float4 o;
  o.x = (v.x - mean) * rs * gv.x + bv.x;
  o.y = (v.y - mean) * rs * gv.y + bv.y;
  o.z = (v.z - mean) * rs * gv.z + bv.z;
  o.w = (v.w - mean) * rs * gv.w + bv.w;
  *(float4*)(y + base + c) = o;
  ushort4 ob;
  ob.x = f2bf(o.x); ob.y = f2bf(o.y); ob.z = f2bf(o.z); ob.w = f2bf(o.w);
  *(ushort4*)(ybf + base + c) = ob;
}

// -------- weight transpose+convert: W [K][N] fp32 -> WT [N][K] bf16 --------
// grid (N/32, K/32, G)
__global__ __launch_bounds__(256) void transpose_w_kernel(
    const float* __restrict__ W, int K, int N, long wgs,
    unsigned short* __restrict__ WT, long wtgs)
{
  __shared__ float T[32][33];
  const float* Wg = W + (long)blockIdx.z * wgs;
  unsigned short* WTg = WT + (long)blockIdx.z * wtgs;
  const int n0 = blockIdx.x * 32, k0 = blockIdx.y * 32;
  const int t = threadIdx.x;
  const int r = t >> 3, c4 = (t & 7) * 4;
  float4 v = *(const float4*)(Wg + (long)(k0 + r) * N + n0 + c4);
  T[r][c4+0] = v.x; T[r][c4+1] = v.y; T[r][c4+2] = v.z; T[r][c4+3] = v.w;
  __syncthreads();
  ushort4 o;
  o.x = f2bf(T[c4+0][r]); o.y = f2bf(T[c4+1][r]);
  o.z = f2bf(T[c4+2][r]); o.w = f2bf(T[c4+3][r]);
  *(ushort4*)(WTg + (long)(n0 + r) * K + k0 + c4) = o;
}

__global__ __launch_bounds__(256) void packb_kernel(
    const float* __restrict__ bq, const float* __restrict__ bk,
    const float* __restrict__ bv, float* __restrict__ qb)
{
  const int i = blockIdx.x * 256 + threadIdx.x;   // 3072
  qb[i] = (i < 1024) ? bq[i] : ((i < 2048) ? bk[i - 1024] : bv[i - 2048]);
}

// ---- bf16 MFMA GEMM: C = A[M][lda] @ BT[N][K]^T + bias. 128x128 tile ----
// grid (N/128, M/128, G). Output bf16 (Cbf) or fp32 (Cf).
__global__ __launch_bounds__(256) void mfma_gemm_kernel(
    const unsigned short* __restrict__ A, int lda, int agoff,
    const unsigned short* __restrict__ BT, long bgoff, int K,
    const float* __restrict__ bias, int biasoff,
    unsigned short* __restrict__ Cbf, float* __restrict__ Cf,
    int ldc, int cgoff)
{
  const int g = blockIdx.z;
  const unsigned short* Ag = A + (long)g * agoff;
  const unsigned short* Bg = BT + (long)g * bgoff;
  const float* biasg = bias + (long)g * biasoff;
  const int row0 = blockIdx.y * 128, col0 = blockIdx.x * 128;
  __shared__ __align__(16) unsigned short As[128][40];
  __shared__ __align__(16) unsigned short Bs[128][40];
  const int tid = threadIdx.x;
  const int srow = tid >> 2, scol = (tid & 3) << 3;
  const int w = tid >> 6, l = tid & 63;
  const int ms = (w & 1) << 6, ns = (w >> 1) << 6;
  const int fr = l & 15, fg = l >> 4;
  f32x4 acc[4][4];
  #pragma unroll
  for (int i = 0; i < 4; ++i)
    #pragma unroll
    for (int j = 0; j < 4; ++j) acc[i][j] = (f32x4)0.0f;

  for (int k0 = 0; k0 < K; k0 += 32) {
    *(short8*)&As[srow][scol]    = *(const short8*)(Ag + (long)(row0 + srow) * lda + k0 + scol);
    *(short8*)&As[srow+64][scol] = *(const short8*)(Ag + (long)(row0 + srow + 64) * lda + k0 + scol);
    *(short8*)&Bs[srow][scol]    = *(const short8*)(Bg + (long)(col0 + srow) * K + k0 + scol);
    *(short8*)&Bs[srow+64][scol] = *(const short8*)(Bg + (long)(col0 + srow + 64) * K + k0 + scol);
    __syncthreads();
    short8 af[4], bfr[4];
    #pragma unroll
    for (int i = 0; i < 4; ++i) af[i] = *(const short8*)&As[ms + i*16 + fr][fg << 3];
    #pragma unroll
    for (int j = 0; j < 4; ++j) bfr[j] = *(const short8*)&Bs[ns + j*16 + fr][fg << 3];
    #pragma unroll
    for (int i = 0; i < 4; ++i)
      #pragma unroll
      for (int j = 0; j < 4; ++j)
        acc[i][j] = __builtin_amdgcn_mfma_f32_16x16x32_bf16(af[i], bfr[j], acc[i][j], 0, 0, 0);
    __syncthreads();
  }

  float bj[4];
  #pragma unroll
  for (int j = 0; j < 4; ++j) bj[j] = biasg[col0 + ns + j*16 + fr];
  #pragma unroll
  for (int i = 0; i < 4; ++i)
    #pragma unroll
    for (int r = 0; r < 4; ++r) {
      const long row = row0 + ms + i*16 + (fg << 2) + r;
      const long cbase = row * ldc + (long)g * cgoff + col0 + ns;
      #pragma unroll
      for (int j = 0; j < 4; ++j) {
        const float v = acc[i][j][r] + bj[j];
        if (Cbf) Cbf[cbase + j*16 + fr] = f2bf(v);
        else     Cf[cbase + j*16 + fr] = v;
      }
    }
}

// ---- grouped dense_in + GLU: h2 = (A@Wx+bx) * relu(A@Wy+by), bf16 out ----
// grid (1024/64, 4096/128, 4). WT [g][2048][256] (x rows 0..1023, y 1024..2047).
__global__ __launch_bounds__(256) void mfma_glu_kernel(
    const unsigned short* __restrict__ A,   // ctx2 [4096][1024]
    const unsigned short* __restrict__ WT,
    const float* __restrict__ bin,          // [4][2048]
    unsigned short* __restrict__ H2)        // [4096][4096]
{
  const int g = blockIdx.z;
  const unsigned short* Ag = A + g * 256;
  const unsigned short* Wg = WT + (long)g * 2048 * 256;
  const float* bg = bin + g * 2048;
  const int row0 = blockIdx.y * 128, col0 = blockIdx.x * 64;
  __shared__ __align__(16) unsigned short As[128][40];
  __shared__ __align__(16) unsigned short Bxs[64][40];
  __shared__ __align__(16) unsigned short Bys[64][40];
  const int tid = threadIdx.x;
  const int srow = tid >> 2, scol = (tid & 3) << 3;
  const int w = tid >> 6, l = tid & 63;
  const int ms = (w & 1) << 6, ns = (w >> 1) << 5;
  const int fr = l & 15, fg = l >> 4;
  f32x4 ax[4][2], ay[4][2];
  #pragma unroll
  for (int i = 0; i < 4; ++i)
    #pragma unroll
    for (int j = 0; j < 2; ++j) { ax[i][j] = (f32x4)0.0f; ay[i][j] = (f32x4)0.0f; }

  for (int k0 = 0; k0 < 256; k0 += 32) {
    *(short8*)&As[srow][scol]    = *(const short8*)(Ag + (long)(row0 + srow) * 1024 + k0 + scol);
    *(short8*)&As[srow+64][scol] = *(const short8*)(Ag + (long)(row0 + srow + 64) * 1024 + k0 + scol);
    *(short8*)&Bxs[srow][scol]   = *(const short8*)(Wg + (long)(col0 + srow) * 256 + k0 + scol);
    *(short8*)&Bys[srow][scol]   = *(const short8*)(Wg + (long)(1024 + col0 + srow) * 256 + k0 + scol);
    __syncthreads();
    short8 af[4], bx[2], by[2];
    #pragma unroll
    for (int i = 0; i < 4; ++i) af[i] = *(const short8*)&As[ms + i*16 + fr][fg << 3];
    #pragma unroll
    for (int j = 0; j < 2; ++j) {
      bx[j] = *(const short8*)&Bxs[ns + j*16 + fr][fg << 3];
      by[j] = *(const short8*)&Bys[ns + j*16 + fr][fg << 3];
    }
    #pragma unroll
    for (int i = 0; i < 4; ++i)
      #pragma unroll
      for (int j = 0; j < 2; ++j) {
        ax[i][j] = __builtin_amdgcn_mfma_f32_16x16x32_bf16(af[i], bx[j], ax[i][j], 0, 0, 0);
        ay[i][j] = __builtin_amdgcn_mfma_f32_16x16x32_bf16(af[i], by[j], ay[i][j], 0, 0, 0);
      }
    __syncthreads();
  }

  float bxb[2], byb[2];
  #pragma unroll
  for (int j = 0; j < 2; ++j) {
    bxb[j] = bg[col0 + ns + j*16 + fr];
    byb[j] = bg[1024 + col0 + ns + j*16 + fr];
  }
  #pragma unroll
  for (int i = 0; i < 4; ++i)
    #pragma unroll
    for (int r = 0; r < 4; ++r) {
      const long row = row0 + ms + i*16 + (fg << 2) + r;
      #pragma unroll
      for (int j = 0; j < 2; ++j) {
        const float xh = ax[i][j][r] + bxb[j];
        const float yh = ay[i][j][r] + byb[j];
        H2[row * 4096 + g * 1024 + col0 + ns + j*16 + fr] = f2bf(xh * fmaxf(yh, 0.0f));
      }
    }
}

// ------------- MFMA attention: scores=-(dist)/16, exp, PV -----------------
// grid (16 s-tiles, 64 heads). qkv bf16 [4096][3072]. scores fp32 out1.
__global__ __launch_bounds__(256) void attn_kernel(
    const unsigned short* __restrict__ qkv, float* __restrict__ ctx,
    float* __restrict__ scores)
{
  const int n = blockIdx.y;
  const int s0 = blockIdx.x * 64;
  const int b = n >> 4, hoff = (n & 15) * 64;
  __shared__ __align__(16) unsigned short Qs[64][72];
  __shared__ __align__(16) unsigned short Ks[64][72];
  __shared__ __align__(16) unsigned short VT[64][72];
  __shared__ __align__(16) unsigned short Ps[64][72];
  __shared__ float q2s[64], k2s[64];
  const int tid = threadIdx.x, w = tid >> 6, l = tid & 63;
  const int fr = l & 15, fg = l >> 4;

  #pragma unroll
  for (int p = 0; p < 2; ++p) {
    const int r = (tid >> 3) + p * 32, c = (tid & 7) << 3;
    *(short8*)&Qs[r][c] = *(const short8*)(qkv + ((long)((s0 + r) * 4 + b)) * 3072 + hoff + c);
  }
  __syncthreads();
  {  // q2 per s-row (wave-parallel: 16 rows/wave, 4 lanes/row)
    const int r = (w << 4) + (l >> 2), dq = (l & 3) << 4;
    float s = 0.f;
    #pragma unroll
    for (int ch = 0; ch < 2; ++ch) {
      short8 v8 = *(const short8*)&Qs[r][dq + (ch << 3)];
      #pragma unroll
      for (int e = 0; e < 8; ++e) { const float f = bf2f((unsigned short)v8[e]); s = fmaf(f, f, s); }
    }
    s += __shfl_xor(s, 1); s += __shfl_xor(s, 2);
    if ((l & 3) == 0) q2s[r] = s;
  }

  f32x4 o[4];
  #pragma unroll
  for (int i = 0; i < 4; ++i) o[i] = (f32x4)0.0f;

  for (int t0 = 0; t0 < 1024; t0 += 64) {
    #pragma unroll
    for (int p = 0; p < 2; ++p) {
      const int r = (tid >> 3) + p * 32, c = (tid & 7) << 3;
      *(short8*)&Ks[r][c] = *(const short8*)(qkv + ((long)((t0 + r) * 4 + b)) * 3072 + 1024 + hoff + c);
    }
    #pragma unroll
    for (int p = 0; p < 2; ++p) {   // V transposed into LDS
      const int d0 = (w << 3) + (p << 5);
      short8 v8 = *(const short8*)(qkv + ((long)((t0 + l) * 4 + b)) * 3072 + 2048 + hoff + d0);
      #pragma unroll
      for (int jj = 0; jj < 8; ++jj) VT[d0 + jj][l] = (unsigned short)v8[jj];
    }
    __syncthreads();
    {  // k2
      const int r = (w << 4) + (l >> 2), dq = (l & 3) << 4;
      float s = 0.f;
      #pragma unroll
      for (int ch = 0; ch < 2; ++ch) {
        short8 v8 = *(const short8*)&Ks[r][dq + (ch << 3)];
        #pragma unroll
        for (int e = 0; e < 8; ++e) { const float f = bf2f((unsigned short)v8[e]); s = fmaf(f, f, s); }
      }
      s += __shfl_xor(s, 1); s += __shfl_xor(s, 2);
      if ((l & 3) == 0) k2s[r] = s;
    }
    __syncthreads();

    // QK^T: wave w owns t-block w*16
    f32x4 c4[4];
    #pragma unroll
    for (int i = 0; i < 4; ++i) c4[i] = (f32x4)0.0f;
    #pragma unroll
    for (int ks = 0; ks < 2; ++ks) {
      const short8 bfr = *(const short8*)&Ks[(w << 4) + fr][(ks << 5) + (fg << 3)];
      #pragma unroll
      for (int i = 0; i < 4; ++i) {
        const short8 af = *(const short8*)&Qs[i*16 + fr][(ks << 5) + (fg << 3)];
        c4[i] = __builtin_amdgcn_mfma_f32_16x16x32_bf16(af, bfr, c4[i], 0, 0, 0);
      }
    }
    const float k2v = k2s[(w << 4) + fr];
    #pragma unroll
    for (int i = 0; i < 4; ++i)
      #pragma unroll
      for (int r4 = 0; r4 < 4; ++r4) {
        const int srow = i*16 + (fg << 2) + r4;
        const float m = (2.0f * c4[i][r4] - q2s[srow] - k2v) * 0.0625f;
        scores[(long)n * 1048576 + (long)(s0 + srow) * 1024 + t0 + (w << 4) + fr] = m;
        Ps[srow][(w << 4) + fr] = f2bf(__expf(m));
      }
    __syncthreads();

    // PV: wave w owns d-block w*16
    #pragma unroll
    for (int ks = 0; ks < 2; ++ks) {
      const short8 vb = *(const short8*)&VT[(w << 4) + fr][(ks << 5) + (fg << 3)];
      #pragma unroll
      for (int i = 0; i < 4; ++i) {
        const short8 pa = *(const short8*)&Ps[i*16 + fr][(ks << 5) + (fg << 3)];
        o[i] = __builtin_amdgcn_mfma_f32_16x16x32_bf16(pa, vb, o[i], 0, 0, 0);
      }
    }
    __syncthreads();
  }

  #pragma unroll
  for (int i = 0; i < 4; ++i)
    #pragma unroll
    for (int r4 = 0; r4 < 4; ++r4) {
      const int srow = s0 + i*16 + (fg << 2) + r4;
      ctx[((long)(srow * 4 + b)) * 1024 + hoff + (w << 4) + fr] = o[i][r4];
    }
}

// -------- residual + per-head LN2 -> bf16 ctx2 -----------------------------
__global__ __launch_bounds__(256) void ln2res_kernel(
    const float* __restrict__ xln, const float* __restrict__ ctx,
    const float* __restrict__ g2, const float* __restrict__ b2,
    unsigned short* __restrict__ ctx2)
{
  const int lane = threadIdx.x & 63;
  const long row = (long)blockIdx.x * 4 + (threadIdx.x >> 6);
  const long idx = row * 64 + lane;
  const float v = xln[idx] + ctx[idx];
  float s = v, ss = v * v;
  #pragma unroll
  for (int off = 32; off > 0; off >>= 1) {
    s  += __shfl_xor(s, off);
    ss += __shfl_xor(ss, off);
  }
  const float mean = s * (1.0f/64.0f);
  const float var  = ss * (1.0f/64.0f) - mean*mean;
  const float rs   = rsqrtf(var + 1e-6f);
  ctx2[idx] = f2bf((v - mean) * rs * g2[lane] + b2[lane]);
}

extern "C" void kernel_launch(void* const* d_in, const int* in_sizes, int n_in,
                              void* d_out, int out_size, void* d_ws, size_t ws_size,
                              hipStream_t stream) {
  const float* hs   = (const float*)d_in[0];
  const float* g1   = (const float*)d_in[1];
  const float* b1   = (const float*)d_in[2];
  const float* g2   = (const float*)d_in[3];
  const float* b2   = (const float*)d_in[4];
  const float* Wq   = (const float*)d_in[5];
  const float* bq   = (const float*)d_in[6];
  const float* Wk   = (const float*)d_in[7];
  const float* bk   = (const float*)d_in[8];
  const float* Wv   = (const float*)d_in[9];
  const float* bv   = (const float*)d_in[10];
  const float* Win  = (const float*)d_in[11];
  const float* bin  = (const float*)d_in[12];
  const float* Wout = (const float*)d_in[13];
  const float* bout = (const float*)d_in[14];
  const float* Wd   = (const float*)d_in[15];
  const float* bd   = (const float*)d_in[16];

  // ws layout (bytes), total ~90.2 MB. Overlays: h2 over xbf+qkv, og over xln.
  char* ws = (char*)d_ws;
  float*          xln   = (float*)(ws + 0);                 // [4096][1024] f32
  unsigned short* xbf   = (unsigned short*)(ws + 16777216); // [4096][1024] bf16
  unsigned short* qkv   = (unsigned short*)(ws + 25165824); // [4096][3072] bf16
  float*          ctx   = (float*)(ws + 50331648);          // [4096][1024] f32
  unsigned short* ctx2  = (unsigned short*)(ws + 67108864); // [4096][1024] bf16
  unsigned short* wqkvT = (unsigned short*)(ws + 75497472); // [3072][1024] bf16
  unsigned short* winT  = (unsigned short*)(ws + 81788928); // [4][2048][256]
  unsigned short* woutT = (unsigned short*)(ws + 85983232); // [4][256][1024]
  unsigned short* wdT   = (unsigned short*)(ws + 88080384); // [1024][1024]
  float*          qkvb  = (float*)(ws + 90177536);          // [3072] f32
  unsigned short* h2    = (unsigned short*)(ws + 16777216); // [4096][4096] bf16
  unsigned short* og    = (unsigned short*)(ws + 0);        // [4096][1024] bf16

  float* out0 = (float*)d_out;           // [S,B,H]
  float* out1 = out0 + 4194304;          // [64,1024,1024]

  ln1_kernel<<<4096, 256, 0, stream>>>(hs, g1, b1, xln, xbf);

  transpose_w_kernel<<<dim3(32,32,1), 256, 0, stream>>>(Wq, 1024, 1024, 0, wqkvT, 0);
  transpose_w_kernel<<<dim3(32,32,1), 256, 0, stream>>>(Wk, 1024, 1024, 0, wqkvT + 1048576, 0);
  transpose_w_kernel<<<dim3(32,32,1), 256, 0, stream>>>(Wv, 1024, 1024, 0, wqkvT + 2097152, 0);
  transpose_w_kernel<<<dim3(64,8,4), 256, 0, stream>>>(Win, 256, 2048, 524288, winT, 524288);
  transpose_w_kernel<<<dim3(8,32,4), 256, 0, stream>>>(Wout, 1024, 256, 262144, woutT, 262144);
  transpose_w_kernel<<<dim3(32,32,1), 256, 0, stream>>>(Wd, 1024, 1024, 0, wdT, 0);
  packb_kernel<<<12, 256, 0, stream>>>(bq, bk, bv, qkvb);

  // QKV: [4096,1024]@[1024,3072] -> qkv bf16
  mfma_gemm_kernel<<<dim3(24,32,1), 256, 0, stream>>>(
      xbf, 1024, 0, wqkvT, 0, 1024, qkvb, 0, qkv, nullptr, 3072, 0);

  attn_kernel<<<dim3(16,64), 256, 0, stream>>>(qkv, ctx, out1);

  ln2res_kernel<<<16384, 256, 0, stream>>>(xln, ctx, g2, b2, ctx2);

  mfma_glu_kernel<<<dim3(16,32,4), 256, 0, stream>>>(ctx2, winT, bin, h2);

  // FFN-out: per group [4096,1024]@[1024,256] -> og bf16
  mfma_gemm_kernel<<<dim3(2,32,4), 256, 0, stream>>>(
      h2, 4096, 1024, woutT, 262144, 1024, bout, 256, og, nullptr, 1024, 256);

  // dense: [4096,1024]@[1024,1024] -> out0 fp32
  mfma_gemm_kernel<<<dim3(8,32,1), 256, 0, stream>>>(
      og, 1024, 0, wdT, 0, 1024, bd, 0, nullptr, out0, 1024, 0);
}

// Round 6
// 268.302 us; speedup vs baseline: 4.1866x; 1.0465x over previous
//
#include <hip/hip_runtime.h>

// TransformerLayer_Combined on gfx950 — bf16 MFMA + global_load_lds pipeline.
// S=1024,B=4,H=1024,NH=16,HPH=64,NF=4,DIN=256,DHID=2048. Outputs fp32.

typedef __attribute__((ext_vector_type(8))) short short8;
typedef __attribute__((ext_vector_type(4))) float f32x4;

__device__ __forceinline__ unsigned short f2bf(float f) {
  union { float f; unsigned u; } x; x.f = f;
  unsigned r = x.u + 0x7FFFu + ((x.u >> 16) & 1u);
  return (unsigned short)(r >> 16);
}
__device__ __forceinline__ float bf2f(unsigned short u) {
  union { float f; unsigned u; } x; x.u = ((unsigned)u) << 16;
  return x.f;
}
// async 16B global->LDS (dest = wave-uniform base + lane*16)
__device__ __forceinline__ void gload16(const unsigned short* g, unsigned short* l) {
  __builtin_amdgcn_global_load_lds(
      (const __attribute__((address_space(1))) unsigned int*)g,
      (__attribute__((address_space(3))) unsigned int*)l, 16, 0, 0);
}

// ---------------- LN1 over H=1024: fp32 (residual) + bf16 (GEMM A) --------
__global__ __launch_bounds__(256) void ln1_kernel(
    const float* __restrict__ x, const float* __restrict__ g,
    const float* __restrict__ b, float* __restrict__ y,
    unsigned short* __restrict__ ybf)
{
  const long base = (long)blockIdx.x * 1024;
  const int c = threadIdx.x * 4;
  float4 v = *(const float4*)(x + base + c);
  float s = v.x + v.y + v.z + v.w;
  float ss = v.x*v.x + v.y*v.y + v.z*v.z + v.w*v.w;
  #pragma unroll
  for (int off = 32; off > 0; off >>= 1) {
    s  += __shfl_xor(s, off);
    ss += __shfl_xor(ss, off);
  }
  __shared__ float sw[4], ssw[4];
  const int wave = threadIdx.x >> 6;
  if ((threadIdx.x & 63) == 0) { sw[wave] = s; ssw[wave] = ss; }
  __syncthreads();
  s  = sw[0] + sw[1] + sw[2] + sw[3];
  ss = ssw[0] + ssw[1] + ssw[2] + ssw[3];
  const float mean = s * (1.0f/1024.0f);
  const float var  = ss * (1.0f/1024.0f) - mean*mean;
  const float rs   = rsqrtf(var + 1e-6f);
  const float4 gv = *(const float4*)(g + c);
  const float4 bv = *(const float4*)(b + c);
  float4 o;
  o.x = (v.x - mean) * rs * gv.x + bv.x;
  o.y = (v.y - mean) * rs * gv.y + bv.y;
  o.z = (v.z - mean) * rs * gv.z + bv.z;
  o.w = (v.w - mean) * rs * gv.w + bv.w;
  *(float4*)(y + base + c) = o;
  ushort4 ob;
  ob.x = f2bf(o.x); ob.y = f2bf(o.y); ob.z = f2bf(o.z); ob.w = f2bf(o.w);
  *(ushort4*)(ybf + base + c) = ob;
}

// -------- weight transpose+convert: W [K][N] fp32 -> WT [N][K] bf16 --------
__global__ __launch_bounds__(256) void transpose_w_kernel(
    const float* __restrict__ W, int K, int N, long wgs,
    unsigned short* __restrict__ WT, long wtgs)
{
  __shared__ float T[32][33];
  const float* Wg = W + (long)blockIdx.z * wgs;
  unsigned short* WTg = WT + (long)blockIdx.z * wtgs;
  const int n0 = blockIdx.x * 32, k0 = blockIdx.y * 32;
  const int t = threadIdx.x;
  const int r = t >> 3, c4 = (t & 7) * 4;
  float4 v = *(const float4*)(Wg + (long)(k0 + r) * N + n0 + c4);
  T[r][c4+0] = v.x; T[r][c4+1] = v.y; T[r][c4+2] = v.z; T[r][c4+3] = v.w;
  __syncthreads();
  ushort4 o;
  o.x = f2bf(T[c4+0][r]); o.y = f2bf(T[c4+1][r]);
  o.z = f2bf(T[c4+2][r]); o.w = f2bf(T[c4+3][r]);
  *(ushort4*)(WTg + (long)(n0 + r) * K + k0 + c4) = o;
}

// merged 1024x1024 transposes: z=0..2 -> wqkvT, z=3 -> wdT
__global__ __launch_bounds__(256) void transpose_qkvd_kernel(
    const float* __restrict__ Wq, const float* __restrict__ Wk,
    const float* __restrict__ Wv, const float* __restrict__ Wd,
    unsigned short* __restrict__ wqkvT, unsigned short* __restrict__ wdT)
{
  const int z = blockIdx.z;
  const float* W = (z == 0) ? Wq : (z == 1) ? Wk : (z == 2) ? Wv : Wd;
  unsigned short* WT = (z == 3) ? wdT : wqkvT + (long)z * 1048576;
  __shared__ float T[32][33];
  const int n0 = blockIdx.x * 32, k0 = blockIdx.y * 32;
  const int t = threadIdx.x;
  const int r = t >> 3, c4 = (t & 7) * 4;
  float4 v = *(const float4*)(W + (long)(k0 + r) * 1024 + n0 + c4);
  T[r][c4+0] = v.x; T[r][c4+1] = v.y; T[r][c4+2] = v.z; T[r][c4+3] = v.w;
  __syncthreads();
  ushort4 o;
  o.x = f2bf(T[c4+0][r]); o.y = f2bf(T[c4+1][r]);
  o.z = f2bf(T[c4+2][r]); o.w = f2bf(T[c4+3][r]);
  *(ushort4*)(WT + (long)(n0 + r) * 1024 + k0 + c4) = o;
}

__global__ __launch_bounds__(256) void packb_kernel(
    const float* __restrict__ bq, const float* __restrict__ bk,
    const float* __restrict__ bv, float* __restrict__ qb)
{
  const int i = blockIdx.x * 256 + threadIdx.x;   // 3072
  qb[i] = (i < 1024) ? bq[i] : ((i < 2048) ? bk[i - 1024] : bv[i - 2048]);
}

// ---- bf16 MFMA GEMM, 128x128 tile, global_load_lds + XOR swizzle --------
// LDS linear [128][32sh]; logical [r][slot s] stored at [r][s^(r&3)];
// source pre-swizzled, ds_read swizzled (rule: both-sides-or-neither).
__global__ __launch_bounds__(256) void mfma_gemm_kernel(
    const unsigned short* __restrict__ A, int lda, long agoff,
    const unsigned short* __restrict__ BT, long bgoff, int K,
    const float* __restrict__ bias, int biasoff,
    unsigned short* __restrict__ Cbf, float* __restrict__ Cf,
    int ldc, int cgoff)
{
  const int g = blockIdx.z;
  const unsigned short* Ag = A + (long)g * agoff;
  const unsigned short* Bg = BT + (long)g * bgoff;
  const float* biasg = bias + (long)g * biasoff;
  const int row0 = blockIdx.y * 128, col0 = blockIdx.x * 128;
  __shared__ __align__(16) unsigned short As[128 * 32];
  __shared__ __align__(16) unsigned short Bs[128 * 32];
  const int tid = threadIdx.x;
  const int w = tid >> 6, l = tid & 63;
  const int ms = (w & 1) << 6, ns = (w >> 1) << 6;
  const int fr = l & 15, fg = l >> 4;
  const int lr = l >> 2;                            // local row in 16-row stripe
  const int sslot = (((l & 3) ^ (lr & 3)) << 3);    // pre-swizzled src col (shorts)
  const int arow = row0 + (w << 4) + lr;
  const int brow = col0 + (w << 4) + lr;
  const int rsw = fr & 3;                           // read swizzle key
  f32x4 acc[4][4];
  #pragma unroll
  for (int i = 0; i < 4; ++i)
    #pragma unroll
    for (int j = 0; j < 4; ++j) acc[i][j] = (f32x4)0.0f;

  for (int k0 = 0; k0 < K; k0 += 32) {
    gload16(Ag + (long)arow * lda + k0 + sslot,        &As[(w << 4) * 32]);
    gload16(Ag + (long)(arow + 64) * lda + k0 + sslot, &As[(64 + (w << 4)) * 32]);
    gload16(Bg + (long)brow * K + k0 + sslot,          &Bs[(w << 4) * 32]);
    gload16(Bg + (long)(brow + 64) * K + k0 + sslot,   &Bs[(64 + (w << 4)) * 32]);
    __syncthreads();
    short8 af[4], bfr[4];
    #pragma unroll
    for (int i = 0; i < 4; ++i)
      af[i] = *(const short8*)&As[(ms + i*16 + fr) * 32 + ((fg ^ rsw) << 3)];
    #pragma unroll
    for (int j = 0; j < 4; ++j)
      bfr[j] = *(const short8*)&Bs[(ns + j*16 + fr) * 32 + ((fg ^ rsw) << 3)];
    #pragma unroll
    for (int i = 0; i < 4; ++i)
      #pragma unroll
      for (int j = 0; j < 4; ++j)
        acc[i][j] = __builtin_amdgcn_mfma_f32_16x16x32_bf16(af[i], bfr[j], acc[i][j], 0, 0, 0);
    __syncthreads();
  }

  float bj[4];
  #pragma unroll
  for (int j = 0; j < 4; ++j) bj[j] = biasg[col0 + ns + j*16 + fr];
  #pragma unroll
  for (int i = 0; i < 4; ++i)
    #pragma unroll
    for (int r = 0; r < 4; ++r) {
      const long row = row0 + ms + i*16 + (fg << 2) + r;
      const long cbase = row * ldc + (long)g * cgoff + col0 + ns;
      #pragma unroll
      for (int j = 0; j < 4; ++j) {
        const float v = acc[i][j][r] + bj[j];
        if (Cbf) Cbf[cbase + j*16 + fr] = f2bf(v);
        else     __builtin_nontemporal_store(v, &Cf[cbase + j*16 + fr]);
      }
    }
}

// ---- grouped dense_in + GLU, 128x64 tile, gload_lds + swizzle -----------
__global__ __launch_bounds__(256) void mfma_glu_kernel(
    const unsigned short* __restrict__ A,   // ctx2 [4096][1024]
    const unsigned short* __restrict__ WT,  // [g][2048][256]
    const float* __restrict__ bin,          // [4][2048]
    unsigned short* __restrict__ H2)        // [4096][4096]
{
  const int g = blockIdx.z;
  const unsigned short* Ag = A + g * 256;
  const unsigned short* Wg = WT + (long)g * 2048 * 256;
  const float* bg = bin + g * 2048;
  const int row0 = blockIdx.y * 128, col0 = blockIdx.x * 64;
  __shared__ __align__(16) unsigned short As[128 * 32];
  __shared__ __align__(16) unsigned short Bxs[64 * 32];
  __shared__ __align__(16) unsigned short Bys[64 * 32];
  const int tid = threadIdx.x;
  const int w = tid >> 6, l = tid & 63;
  const int ms = (w & 1) << 6, ns = (w >> 1) << 5;
  const int fr = l & 15, fg = l >> 4;
  const int lr = l >> 2;
  const int sslot = (((l & 3) ^ (lr & 3)) << 3);
  const int arow = row0 + (w << 4) + lr;
  const int brow = col0 + (w << 4) + lr;
  const int rsw = fr & 3;
  f32x4 ax[4][2], ay[4][2];
  #pragma unroll
  for (int i = 0; i < 4; ++i)
    #pragma unroll
    for (int j = 0; j < 2; ++j) { ax[i][j] = (f32x4)0.0f; ay[i][j] = (f32x4)0.0f; }

  for (int k0 = 0; k0 < 256; k0 += 32) {
    gload16(Ag + (long)arow * 1024 + k0 + sslot,        &As[(w << 4) * 32]);
    gload16(Ag + (long)(arow + 64) * 1024 + k0 + sslot, &As[(64 + (w << 4)) * 32]);
    gload16(Wg + (long)brow * 256 + k0 + sslot,         &Bxs[(w << 4) * 32]);
    gload16(Wg + (long)(1024 + brow) * 256 + k0 + sslot,&Bys[(w << 4) * 32]);
    __syncthreads();
    short8 af[4], bx[2], by[2];
    #pragma unroll
    for (int i = 0; i < 4; ++i)
      af[i] = *(const short8*)&As[(ms + i*16 + fr) * 32 + ((fg ^ rsw) << 3)];
    #pragma unroll
    for (int j = 0; j < 2; ++j) {
      bx[j] = *(const short8*)&Bxs[(ns + j*16 + fr) * 32 + ((fg ^ rsw) << 3)];
      by[j] = *(const short8*)&Bys[(ns + j*16 + fr) * 32 + ((fg ^ rsw) << 3)];
    }
    #pragma unroll
    for (int i = 0; i < 4; ++i)
      #pragma unroll
      for (int j = 0; j < 2; ++j) {
        ax[i][j] = __builtin_amdgcn_mfma_f32_16x16x32_bf16(af[i], bx[j], ax[i][j], 0, 0, 0);
        ay[i][j] = __builtin_amdgcn_mfma_f32_16x16x32_bf16(af[i], by[j], ay[i][j], 0, 0, 0);
      }
    __syncthreads();
  }

  float bxb[2], byb[2];
  #pragma unroll
  for (int j = 0; j < 2; ++j) {
    bxb[j] = bg[col0 + ns + j*16 + fr];
    byb[j] = bg[1024 + col0 + ns + j*16 + fr];
  }
  #pragma unroll
  for (int i = 0; i < 4; ++i)
    #pragma unroll
    for (int r = 0; r < 4; ++r) {
      const long row = row0 + ms + i*16 + (fg << 2) + r;
      #pragma unroll
      for (int j = 0; j < 2; ++j) {
        const float xh = ax[i][j][r] + bxb[j];
        const float yh = ay[i][j][r] + byb[j];
        H2[row * 4096 + g * 1024 + col0 + ns + j*16 + fr] = f2bf(xh * fmaxf(yh, 0.0f));
      }
    }
}

// -------- per-row sum-of-squares for q and k: [64 heads][1024 s] ----------
__global__ __launch_bounds__(256) void sumsq_kernel(
    const unsigned short* __restrict__ qkv,
    float* __restrict__ q2g, float* __restrict__ k2g)
{
  const int sb = blockIdx.x;              // s*4+b
  const int s = sb >> 2, b = sb & 3;
  const int h = threadIdx.x >> 4, e = threadIdx.x & 15;
  const long base = (long)sb * 3072 + h * 64 + e * 4;
  ushort4 qv = *(const ushort4*)(qkv + base);
  ushort4 kv = *(const ushort4*)(qkv + base + 1024);
  float sq = 0.f, sk = 0.f, f;
  f = bf2f(qv.x); sq = fmaf(f,f,sq); f = bf2f(qv.y); sq = fmaf(f,f,sq);
  f = bf2f(qv.z); sq = fmaf(f,f,sq); f = bf2f(qv.w); sq = fmaf(f,f,sq);
  f = bf2f(kv.x); sk = fmaf(f,f,sk); f = bf2f(kv.y); sk = fmaf(f,f,sk);
  f = bf2f(kv.z); sk = fmaf(f,f,sk); f = bf2f(kv.w); sk = fmaf(f,f,sk);
  #pragma unroll
  for (int off = 1; off < 16; off <<= 1) { sq += __shfl_xor(sq, off); sk += __shfl_xor(sk, off); }
  if (e == 0) {
    q2g[(b * 16 + h) * 1024 + s] = sq;
    k2g[(b * 16 + h) * 1024 + s] = sk;
  }
}

// -------- V transpose: qkv v-part [s][b,h,d] -> vt [n][d][s] bf16 ----------
__global__ __launch_bounds__(256) void vtrans_kernel(
    const unsigned short* __restrict__ qkv, unsigned short* __restrict__ vt)
{
  __shared__ unsigned short T[64][72];
  const int n = blockIdx.y, s0 = blockIdx.x * 64;
  const int b = n >> 4, hoff = (n & 15) * 64;
  const int tid = threadIdx.x;
  #pragma unroll
  for (int p = 0; p < 2; ++p) {
    const int r = (tid >> 3) + p * 32, c = (tid & 7) << 3;
    *(short8*)&T[r][c] = *(const short8*)(qkv + ((long)((s0 + r) * 4 + b)) * 3072 + 2048 + hoff + c);
  }
  __syncthreads();
  #pragma unroll
  for (int p = 0; p < 2; ++p) {
    const int d = (tid >> 3) + p * 32, sc = (tid & 7) << 3;
    short8 o;
    #pragma unroll
    for (int j = 0; j < 8; ++j) o[j] = (short)T[sc + j][d];
    *(short8*)(vt + ((long)n * 64 + d) * 1024 + s0 + sc) = o;
  }
}

// ------------- MFMA attention: scores=-(dist)/16, exp, PV -----------------
// grid (16 s-tiles, 64 heads). K/VT staged via gload_lds, XOR-swizzled (8 slots).
__global__ __launch_bounds__(256) void attn_kernel(
    const unsigned short* __restrict__ qkv, const unsigned short* __restrict__ vt,
    const float* __restrict__ q2g, const float* __restrict__ k2g,
    float* __restrict__ ctx, float* __restrict__ scores)
{
  const int n = blockIdx.y;
  const int s0 = blockIdx.x * 64;
  const int b = n >> 4, hoff = (n & 15) * 64;
  __shared__ __align__(16) unsigned short Qs[64][72];
  __shared__ __align__(16) unsigned short Ks[64 * 64];   // linear swizzled
  __shared__ __align__(16) unsigned short VTl[64 * 64];  // linear swizzled
  __shared__ __align__(16) unsigned short Ps[64][72];
  __shared__ float q2s[64];
  const int tid = threadIdx.x, w = tid >> 6, l = tid & 63;
  const int fr = l & 15, fg = l >> 4;
  const int lr8 = l >> 3, ls8 = l & 7;
  const int sslot = ((ls8 ^ lr8) << 3);    // pre-swizzled src col (shorts)
  const int rsw = fr & 7;                  // read swizzle key

  #pragma unroll
  for (int p = 0; p < 2; ++p) {
    const int r = (tid >> 3) + p * 32, c = (tid & 7) << 3;
    *(short8*)&Qs[r][c] = *(const short8*)(qkv + ((long)((s0 + r) * 4 + b)) * 3072 + hoff + c);
  }
  if (tid < 64) q2s[tid] = q2g[n * 1024 + s0 + tid];

  f32x4 o[4];
  #pragma unroll
  for (int i = 0; i < 4; ++i) o[i] = (f32x4)0.0f;

  for (int t0 = 0; t0 < 1024; t0 += 64) {
    #pragma unroll
    for (int p = 0; p < 2; ++p) {
      const int rowb = p * 32 + w * 8;
      gload16(qkv + ((long)((t0 + rowb + lr8) * 4 + b)) * 3072 + 1024 + hoff + sslot,
              &Ks[rowb * 64]);
      gload16(vt + ((long)n * 64 + rowb + lr8) * 1024 + t0 + sslot,
              &VTl[rowb * 64]);
    }
    const float k2v = k2g[n * 1024 + t0 + (w << 4) + fr];
    __syncthreads();

    // QK^T: wave w owns t-block w*16
    f32x4 c4[4];
    #pragma unroll
    for (int i = 0; i < 4; ++i) c4[i] = (f32x4)0.0f;
    #pragma unroll
    for (int ks = 0; ks < 2; ++ks) {
      const short8 bfr = *(const short8*)&Ks[((w << 4) + fr) * 64 + ((((ks << 2) + fg) ^ rsw) << 3)];
      #pragma unroll
      for (int i = 0; i < 4; ++i) {
        const short8 af = *(const short8*)&Qs[i*16 + fr][(ks << 5) + (fg << 3)];
        c4[i] = __builtin_amdgcn_mfma_f32_16x16x32_bf16(af, bfr, c4[i], 0, 0, 0);
      }
    }
    #pragma unroll
    for (int i = 0; i < 4; ++i)
      #pragma unroll
      for (int r4 = 0; r4 < 4; ++r4) {
        const int srow = i*16 + (fg << 2) + r4;
        const float m = (2.0f * c4[i][r4] - q2s[srow] - k2v) * 0.0625f;
        __builtin_nontemporal_store(m,
            &scores[(long)n * 1048576 + (long)(s0 + srow) * 1024 + t0 + (w << 4) + fr]);
        Ps[srow][(w << 4) + fr] = f2bf(__expf(m));
      }
    __syncthreads();

    // PV: wave w owns d-block w*16
    #pragma unroll
    for (int ks = 0; ks < 2; ++ks) {
      const short8 vb = *(const short8*)&VTl[((w << 4) + fr) * 64 + ((((ks << 2) + fg) ^ rsw) << 3)];
      #pragma unroll
      for (int i = 0; i < 4; ++i) {
        const short8 pa = *(const short8*)&Ps[i*16 + fr][(ks << 5) + (fg << 3)];
        o[i] = __builtin_amdgcn_mfma_f32_16x16x32_bf16(pa, vb, o[i], 0, 0, 0);
      }
    }
    __syncthreads();
  }

  #pragma unroll
  for (int i = 0; i < 4; ++i)
    #pragma unroll
    for (int r4 = 0; r4 < 4; ++r4) {
      const int srow = s0 + i*16 + (fg << 2) + r4;
      ctx[((long)(srow * 4 + b)) * 1024 + hoff + (w << 4) + fr] = o[i][r4];
    }
}

// -------- residual + per-head LN2 -> bf16 ctx2 -----------------------------
__global__ __launch_bounds__(256) void ln2res_kernel(
    const float* __restrict__ xln, const float* __restrict__ ctx,
    const float* __restrict__ g2, const float* __restrict__ b2,
    unsigned short* __restrict__ ctx2)
{
  const int lane = threadIdx.x & 63;
  const long row = (long)blockIdx.x * 4 + (threadIdx.x >> 6);
  const long idx = row * 64 + lane;
  const float v = xln[idx] + ctx[idx];
  float s = v, ss = v * v;
  #pragma unroll
  for (int off = 32; off > 0; off >>= 1) {
    s  += __shfl_xor(s, off);
    ss += __shfl_xor(ss, off);
  }
  const float mean = s * (1.0f/64.0f);
  const float var  = ss * (1.0f/64.0f) - mean*mean;
  const float rs   = rsqrtf(var + 1e-6f);
  ctx2[idx] = f2bf((v - mean) * rs * g2[lane] + b2[lane]);
}

extern "C" void kernel_launch(void* const* d_in, const int* in_sizes, int n_in,
                              void* d_out, int out_size, void* d_ws, size_t ws_size,
                              hipStream_t stream) {
  const float* hs   = (const float*)d_in[0];
  const float* g1   = (const float*)d_in[1];
  const float* b1   = (const float*)d_in[2];
  const float* g2   = (const float*)d_in[3];
  const float* b2   = (const float*)d_in[4];
  const float* Wq   = (const float*)d_in[5];
  const float* bq   = (const float*)d_in[6];
  const float* Wk   = (const float*)d_in[7];
  const float* bk   = (const float*)d_in[8];
  const float* Wv   = (const float*)d_in[9];
  const float* bv   = (const float*)d_in[10];
  const float* Win  = (const float*)d_in[11];
  const float* bin  = (const float*)d_in[12];
  const float* Wout = (const float*)d_in[13];
  const float* bout = (const float*)d_in[14];
  const float* Wd   = (const float*)d_in[15];
  const float* bd   = (const float*)d_in[16];

  // ws layout (bytes), ~94.5 MB total. Overlays: h2 over xbf+qkv, og over xln.
  char* ws = (char*)d_ws;
  float*          xln   = (float*)(ws + 0);                 // [4096][1024] f32
  unsigned short* xbf   = (unsigned short*)(ws + 16777216); // [4096][1024] bf16
  unsigned short* qkv   = (unsigned short*)(ws + 25165824); // [4096][3072] bf16
  float*          ctx   = (float*)(ws + 50331648);          // [4096][1024] f32
  unsigned short* ctx2  = (unsigned short*)(ws + 67108864); // [4096][1024] bf16
  unsigned short* wqkvT = (unsigned short*)(ws + 75497472); // [3072][1024] bf16
  unsigned short* winT  = (unsigned short*)(ws + 81788928); // [4][2048][256]
  unsigned short* woutT = (unsigned short*)(ws + 85983232); // [4][256][1024]
  unsigned short* wdT   = (unsigned short*)(ws + 88080384); // [1024][1024]
  float*          qkvb  = (float*)(ws + 90177536);          // [3072] f32
  unsigned short* vt    = (unsigned short*)(ws + 90189824); // [64][64][1024] bf16
  float*          q2g   = (float*)(ws + 98578432);          // [64][1024] f32
  float*          k2g   = (float*)(ws + 98840576);          // [64][1024] f32
  unsigned short* h2    = (unsigned short*)(ws + 16777216); // [4096][4096] bf16
  unsigned short* og    = (unsigned short*)(ws + 0);        // [4096][1024] bf16

  float* out0 = (float*)d_out;           // [S,B,H]
  float* out1 = out0 + 4194304;          // [64,1024,1024]

  ln1_kernel<<<4096, 256, 0, stream>>>(hs, g1, b1, xln, xbf);

  transpose_qkvd_kernel<<<dim3(32,32,4), 256, 0, stream>>>(Wq, Wk, Wv, Wd, wqkvT, wdT);
  transpose_w_kernel<<<dim3(64,8,4), 256, 0, stream>>>(Win, 256, 2048, 524288, winT, 524288);
  transpose_w_kernel<<<dim3(8,32,4), 256, 0, stream>>>(Wout, 1024, 256, 262144, woutT, 262144);
  packb_kernel<<<12, 256, 0, stream>>>(bq, bk, bv, qkvb);

  // QKV: [4096,1024]@[1024,3072] -> qkv bf16
  mfma_gemm_kernel<<<dim3(24,32,1), 256, 0, stream>>>(
      xbf, 1024, 0, wqkvT, 0, 1024, qkvb, 0, qkv, nullptr, 3072, 0);

  sumsq_kernel<<<4096, 256, 0, stream>>>(qkv, q2g, k2g);
  vtrans_kernel<<<dim3(16,64), 256, 0, stream>>>(qkv, vt);

  attn_kernel<<<dim3(16,64), 256, 0, stream>>>(qkv, vt, q2g, k2g, ctx, out1);

  ln2res_kernel<<<16384, 256, 0, stream>>>(xln, ctx, g2, b2, ctx2);

  mfma_glu_kernel<<<dim3(16,32,4), 256, 0, stream>>>(ctx2, winT, bin, h2);

  // FFN-out: per group [4096,1024]@[1024,256] -> og bf16
  mfma_gemm_kernel<<<dim3(2,32,4), 256, 0, stream>>>(
      h2, 4096, 1024, woutT, 262144, 1024, bout, 256, og, nullptr, 1024, 256);

  // dense: [4096,1024]@[1024,1024] -> out0 fp32 (NT store)
  mfma_gemm_kernel<<<dim3(8,32,1), 256, 0, stream>>>(
      og, 1024, 0, wdT, 0, 1024, bd, 0, nullptr, out0, 1024, 0);
}